// Round 1
// baseline (50.983 us; speedup 1.0000x reference)
//
#include <hip/hip_runtime.h>
#include <math.h>

#define OBS 512
#define ATT 128
#define NA 16
#define RPB 8   // (b,e) rows per block

// Kernel 0: ws <- Wphi^T  (WphiT[k][dd] = Wphi[dd][k]), 128x512 fp32 = 256KB
__global__ void transpose_wphi_k(const float* __restrict__ wphi,
                                 float* __restrict__ wphiT) {
  int idx = blockIdx.x * 256 + threadIdx.x;   // 0..65535
  int k  = idx >> 9;
  int dd = idx & 511;
  wphiT[idx] = wphi[dd * ATT + k];
}

__device__ __forceinline__ void fma4(float4& acc, float a, float4 w) {
  acc.x = fmaf(a, w.x, acc.x);
  acc.y = fmaf(a, w.y, acc.y);
  acc.z = fmaf(a, w.z, acc.z);
  acc.w = fmaf(a, w.w, acc.w);
}

__launch_bounds__(256)
__global__ void entity_attn_k(const float* __restrict__ A,     // (4096,512)
                              const float* __restrict__ V,     // (4096,16,512)
                              const float* __restrict__ Wpsi,  // (512,128)
                              const float* __restrict__ WphiT, // (128,512) ws
                              float* __restrict__ Out)         // (4096,16)
{
  // qtS: q transposed, qt[k][r], 4KB
  __shared__ __align__(16) float qtS[ATT * RPB];
  // regB multi-use 48KB:
  //   phase B: At[d][r] = regB[d*8+r] (16KB) ; qpart[ds][r][k] at +4096 (32KB)
  //   phase C: upart[kh][r][dd] = regB[(kh*8+r)*512+dd] (32KB)
  //   phase D: u[r][dd] = regB[8192 + r*512+dd] (16KB)
  __shared__ __align__(16) float regB[12288];

  const int tid  = threadIdx.x;
  const int lane = tid & 63;
  const int wave = tid >> 6;
  const int g0   = blockIdx.x * RPB;

  // ---- stage A transposed: At[d][r] = A[g0+r][d] ----
  {
    const int r  = tid & 7;
    const int c  = tid >> 3;       // 0..31
    const int d0 = c * 16;
    const float4* arow = (const float4*)(A + (size_t)(g0 + r) * OBS + d0);
    float4 v0 = arow[0], v1 = arow[1], v2 = arow[2], v3 = arow[3];
    float tmp[16] = {v0.x,v0.y,v0.z,v0.w, v1.x,v1.y,v1.z,v1.w,
                     v2.x,v2.y,v2.z,v2.w, v3.x,v3.y,v3.z,v3.w};
#pragma unroll
    for (int j = 0; j < 16; ++j) regB[(d0 + j) * 8 + r] = tmp[j];
  }
  __syncthreads();

  // ---- phase B: q partials. thread = (k-quad kg, d-split ds) ----
  {
    const int kg = tid & 31;
    const int ds = tid >> 5;
    const int k0 = kg * 4;
    const int dbase = ds * 64;
    float4 acc[8];
#pragma unroll
    for (int r = 0; r < 8; ++r) acc[r] = make_float4(0.f, 0.f, 0.f, 0.f);
    const float4* wp4 = (const float4*)Wpsi;
#pragma unroll 4
    for (int i = 0; i < 64; ++i) {
      const int d = dbase + i;
      float4 w = wp4[d * 32 + kg];                       // Wpsi[d][k0..k0+4)
      const float4* at4 = (const float4*)(regB + d * 8); // At[d][0..8) broadcast
      float4 a01 = at4[0];
      float4 a23 = at4[1];
      fma4(acc[0], a01.x, w); fma4(acc[1], a01.y, w);
      fma4(acc[2], a01.z, w); fma4(acc[3], a01.w, w);
      fma4(acc[4], a23.x, w); fma4(acc[5], a23.y, w);
      fma4(acc[6], a23.z, w); fma4(acc[7], a23.w, w);
    }
    float4* qp4 = (float4*)regB;
#pragma unroll
    for (int r = 0; r < 8; ++r)
      qp4[(4096 + (ds * 8 + r) * 128 + k0) >> 2] = acc[r];
  }
  __syncthreads();

  // ---- q-reduce over the 8 d-splits -> qt[k][r] ----
  {
    const int r  = tid & 7;
    const int kq = tid >> 3;   // 0..31
    const int k0 = kq * 4;
    const float4* qp4 = (const float4*)regB;
    float4 s = make_float4(0.f, 0.f, 0.f, 0.f);
#pragma unroll
    for (int ds = 0; ds < 8; ++ds) {
      float4 p = qp4[(4096 + (ds * 8 + r) * 128 + k0) >> 2];
      s.x += p.x; s.y += p.y; s.z += p.z; s.w += p.w;
    }
    qtS[(k0 + 0) * 8 + r] = s.x;
    qtS[(k0 + 1) * 8 + r] = s.y;
    qtS[(k0 + 2) * 8 + r] = s.z;
    qtS[(k0 + 3) * 8 + r] = s.w;
  }
  __syncthreads();

  // ---- phase C: u[r][dd] = sum_k q[r][k] * WphiT[k][dd] ----
  // wave = (k-half kh, dd-half ddh); q column held in regs, broadcast by shfl
  {
    const int kh  = wave & 1;
    const int ddh = wave >> 1;
    const int dd0 = ddh * 256 + lane * 4;
    const int kq  = kh * 64 + lane;
    const float4* qt4 = (const float4*)qtS;
    float4 qa = qt4[kq * 2];
    float4 qb = qt4[kq * 2 + 1];
    float q8[8] = {qa.x, qa.y, qa.z, qa.w, qb.x, qb.y, qb.z, qb.w};
    float4 acc[8];
#pragma unroll
    for (int r = 0; r < 8; ++r) acc[r] = make_float4(0.f, 0.f, 0.f, 0.f);
    const float4* wt4 = (const float4*)WphiT;
#pragma unroll 4
    for (int kk = 0; kk < 64; ++kk) {
      const int k = kh * 64 + kk;
      float4 wt = wt4[(k * 512 + dd0) >> 2];
#pragma unroll
      for (int r = 0; r < 8; ++r) {
        float qv = __shfl(q8[r], kk, 64);
        fma4(acc[r], qv, wt);
      }
    }
    float4* up4 = (float4*)regB;
#pragma unroll
    for (int r = 0; r < 8; ++r)
      up4[((kh * 8 + r) * 512 + dd0) >> 2] = acc[r];
  }
  __syncthreads();

  // ---- u-reduce over the 2 k-halves -> u at regB+8192 ----
  {
    const int r   = tid >> 5;
    const int dd0 = (tid & 31) * 16;
    const float4* up4 = (const float4*)regB;
    float4* u4 = (float4*)(regB + 8192);
#pragma unroll
    for (int seg = 0; seg < 4; ++seg) {
      const int o = r * 512 + dd0 + seg * 4;
      float4 x = up4[o >> 2];
      float4 y = up4[(4096 + o) >> 2];
      x.x += y.x; x.y += y.y; x.z += y.z; x.w += y.w;
      u4[o >> 2] = x;
    }
  }
  __syncthreads();

  // ---- phase D: stream visible, beta = u.v, softmax over a ----
  const float* u = regB + 8192;
  const float4* V4 = (const float4*)V;
#pragma unroll
  for (int rr = 0; rr < 2; ++rr) {
    const int r = wave * 2 + rr;
    const size_t g = (size_t)(g0 + r);
    const float4* vrow = V4 + g * 2048;   // 16 x 512 floats
    const float4* ur = (const float4*)(u + r * 512);
    float4 uf0 = ur[lane * 2];
    float4 uf1 = ur[lane * 2 + 1];
    float acc[16];
#pragma unroll
    for (int a = 0; a < 16; ++a) {
      float4 v0 = vrow[a * 128 + lane * 2];
      float4 v1 = vrow[a * 128 + lane * 2 + 1];
      float s;
      s = uf0.x * v0.x;
      s = fmaf(uf0.y, v0.y, s);
      s = fmaf(uf0.z, v0.z, s);
      s = fmaf(uf0.w, v0.w, s);
      s = fmaf(uf1.x, v1.x, s);
      s = fmaf(uf1.y, v1.y, s);
      s = fmaf(uf1.z, v1.z, s);
      s = fmaf(uf1.w, v1.w, s);
      acc[a] = s;
    }
#pragma unroll
    for (int a = 0; a < 16; ++a) {
      float v = acc[a];
      v += __shfl_xor(v, 32, 64);
      v += __shfl_xor(v, 16, 64);
      v += __shfl_xor(v,  8, 64);
      v += __shfl_xor(v,  4, 64);
      v += __shfl_xor(v,  2, 64);
      v += __shfl_xor(v,  1, 64);
      acc[a] = v;
    }
    float mx = acc[0];
#pragma unroll
    for (int a = 1; a < 16; ++a) mx = fmaxf(mx, acc[a]);
    float ssum = 0.f;
#pragma unroll
    for (int a = 0; a < 16; ++a) { acc[a] = __expf(acc[a] - mx); ssum += acc[a]; }
    const float inv = 1.0f / ssum;
    if (lane == 0) {
      float4* o4 = (float4*)(Out + g * 16);
      o4[0] = make_float4(acc[0]  * inv, acc[1]  * inv, acc[2]  * inv, acc[3]  * inv);
      o4[1] = make_float4(acc[4]  * inv, acc[5]  * inv, acc[6]  * inv, acc[7]  * inv);
      o4[2] = make_float4(acc[8]  * inv, acc[9]  * inv, acc[10] * inv, acc[11] * inv);
      o4[3] = make_float4(acc[12] * inv, acc[13] * inv, acc[14] * inv, acc[15] * inv);
    }
  }
}

extern "C" void kernel_launch(void* const* d_in, const int* in_sizes, int n_in,
                              void* d_out, int out_size, void* d_ws, size_t ws_size,
                              hipStream_t stream) {
  (void)in_sizes; (void)n_in; (void)out_size; (void)ws_size;
  const float* A    = (const float*)d_in[0];  // agent_observation (128,32,512)
  const float* V    = (const float*)d_in[1];  // visible_observations (128,32,16,512)
  const float* Wpsi = (const float*)d_in[2];  // (512,128)
  const float* Wphi = (const float*)d_in[3];  // (512,128)
  float* Out = (float*)d_out;                 // (128,32,16) fp32
  float* WphiT = (float*)d_ws;                // 256KB scratch

  transpose_wphi_k<<<256, 256, 0, stream>>>(Wphi, WphiT);
  entity_attn_k<<<512, 256, 0, stream>>>(A, V, Wpsi, WphiT, Out);
}